// Round 6
// baseline (645.340 us; speedup 1.0000x reference)
//
#include <hip/hip_runtime.h>

#define HID 128
#define LDP 136   // padded LDS row stride in bf16 elems (272 B)

typedef short s16x8 __attribute__((ext_vector_type(8)));
typedef float f32x4 __attribute__((ext_vector_type(4)));
typedef float f32x2 __attribute__((ext_vector_type(2)));

__device__ __forceinline__ float bf2f(unsigned int u) {
  union { unsigned int i; float f; } v; v.i = u << 16; return v.f;
}
__device__ __forceinline__ float asf(unsigned int u) {
  union { unsigned int i; float f; } v; v.i = u; return v.f;
}
__device__ __forceinline__ unsigned short f2bf(float f) {
  union { float f; unsigned int i; } v; v.f = f;
  unsigned int r = v.i + 0x7fffu + ((v.i >> 16) & 1u);
  return (unsigned short)(r >> 16);
}
// f32 -> fp8 e4m3 byte (RNE, via HW cvt)
__device__ __forceinline__ unsigned char f2fp8(float f) {
  unsigned int p = __builtin_amdgcn_cvt_pk_fp8_f32(f, f, 0u, false);
  return (unsigned char)(p & 0xffu);
}

// ---------------- zero fill (vectorized) ----------------
__global__ void k_zero4(float4* __restrict__ p, size_t n4) {
  size_t i = (size_t)blockIdx.x * blockDim.x + threadIdx.x;
  if (i < n4) p[i] = (float4){0.f, 0.f, 0.f, 0.f};
}

// ---------------- counting sort ----------------
__global__ void k_hist(const int* __restrict__ dst, int* __restrict__ deg, int nE) {
  int e = blockIdx.x * blockDim.x + threadIdx.x;
  if (e < nE) atomicAdd(&deg[dst[e]], 1);
}

__global__ void k_scanA(const int* __restrict__ deg, int* __restrict__ bsum) {
  __shared__ int ss[256];
  int t = threadIdx.x;
  ss[t] = deg[blockIdx.x * 256 + t];
  __syncthreads();
  for (int off = 128; off; off >>= 1) {
    if (t < off) ss[t] += ss[t + off];
    __syncthreads();
  }
  if (t == 0) bsum[blockIdx.x] = ss[0];
}

__global__ void k_scanB(const int* __restrict__ bsum, int* __restrict__ bsumx, int NB) {
  __shared__ int sd[512];
  int t = threadIdx.x;
  int v = (t < NB) ? bsum[t] : 0;
  sd[t] = v;
  __syncthreads();
  for (int off = 1; off < 512; off <<= 1) {
    int a = (t >= off) ? sd[t - off] : 0;
    __syncthreads();
    sd[t] += a;
    __syncthreads();
  }
  if (t < NB) bsumx[t] = sd[t] - v;
}

// exclusive scan to BOTH cursor (mutated by scatter) and rowptr (kept)
__global__ void k_scanC(const int* __restrict__ deg, const int* __restrict__ bsumx,
                        int* __restrict__ cursor, int* __restrict__ rowptr) {
  __shared__ int ss[256];
  int t = threadIdx.x, i = blockIdx.x * 256 + t;
  int v = deg[i];
  ss[t] = v;
  __syncthreads();
  for (int off = 1; off < 256; off <<= 1) {
    int a = (t >= off) ? ss[t - off] : 0;
    __syncthreads();
    ss[t] += a;
    __syncthreads();
  }
  int ex = ss[t] - v + bsumx[blockIdx.x];
  cursor[i] = ex;
  rowptr[i] = ex;
}

// permute: only src and edge id (8 B random writes; ea gathered later from L3)
__global__ void k_scatter(const int* __restrict__ src, const int* __restrict__ dst,
                          int* __restrict__ cursor,
                          int* __restrict__ src_s, int* __restrict__ esort, int nE) {
  int e = blockIdx.x * blockDim.x + threadIdx.x;
  if (e >= nE) return;
  int d = dst[e];
  int pos = atomicAdd(&cursor[d], 1);
  src_s[pos] = src[e];
  esort[pos] = e;
}

// ---------------- transpose weights to bf16 ----------------
__global__ void k_prep_w(const float* __restrict__ ew2, const float* __restrict__ cw1,
                         const float* __restrict__ cw2, unsigned short* __restrict__ wT) {
  int idx = blockIdx.x * blockDim.x + threadIdx.x;
  if (idx >= 7 * 16384) return;
  int m = idx >> 14, i = idx & 16383;
  int n = i >> 7, k = i & 127;
  const float* s = (m == 0) ? ew2 : (m <= 3 ? cw1 + (size_t)(m - 1) * 16384
                                            : cw2 + (size_t)(m - 4) * 16384);
  wT[idx] = f2bf(s[k * 128 + n]);
}

// ---------------- node encoder ----------------
__global__ void k_node_enc(const float* __restrict__ x, const float* __restrict__ w,
                           const float* __restrict__ b, unsigned short* __restrict__ h16, int nN) {
  int idx = blockIdx.x * blockDim.x + threadIdx.x;
  if (idx >= nN * HID) return;
  int i = idx >> 7, j = idx & 127;
  float acc = b[j];
  const float* xr = x + (size_t)i * 7;
#pragma unroll
  for (int k = 0; k < 7; ++k) acc += xr[k] * w[k * HID + j];
  h16[idx] = f2bf(acc);
}

// ---------------- one-time edge encoder GEMM -> e8 (fp8, sorted order) ----------------
// gathers ea rows through esort (ea is L3-resident)
__global__ void __launch_bounds__(256) k_edge_gemm(
    const float* __restrict__ ea, const int* __restrict__ esort,
    const float* __restrict__ ew1, const float* __restrict__ eb1,
    const unsigned short* __restrict__ w2t, const float* __restrict__ eb2,
    unsigned char* __restrict__ e8, int nE) {
  __shared__ __attribute__((aligned(16))) unsigned short ts1[128 * LDP];
  __shared__ float eaL[384];
  __shared__ int esL[128];
  int tid = threadIdx.x;
  int e0 = blockIdx.x * 128;                      // nE % 128 == 0
  if (tid < 128) esL[tid] = esort[e0 + tid];
  __syncthreads();
  for (int i = tid; i < 384; i += 256) {
    int r = i / 3, c = i - r * 3;
    eaL[i] = ea[(size_t)esL[r] * 3 + c];
  }
  __syncthreads();
  {
    int j = tid & 127, r0 = (tid >> 7) * 64;
    float wa = ew1[j], wb = ew1[HID + j], wc = ew1[2 * HID + j], bj = eb1[j];
    for (int r = r0; r < r0 + 64; ++r) {
      float a = bj + eaL[r * 3] * wa + eaL[r * 3 + 1] * wb + eaL[r * 3 + 2] * wc;
      ts1[r * LDP + j] = f2bf(fmaxf(a, 0.f));
    }
  }
  __syncthreads();
  int wave = tid >> 6, lane = tid & 63;
  int l15 = lane & 15, quad = lane >> 4;
  int rbase = (wave >> 1) * 64, nbase = (wave & 1) * 64;
  f32x4 acc[4][4];
#pragma unroll
  for (int i = 0; i < 4; ++i)
#pragma unroll
    for (int j = 0; j < 4; ++j) acc[i][j] = (f32x4){0.f, 0.f, 0.f, 0.f};
  for (int kc = 0; kc < 4; ++kc) {
    int k0 = kc * 32 + quad * 8;
    s16x8 af[4], bf[4];
#pragma unroll
    for (int t = 0; t < 4; ++t)
      af[t] = *(const s16x8*)&ts1[(rbase + t * 16 + l15) * LDP + k0];
#pragma unroll
    for (int t = 0; t < 4; ++t)
      bf[t] = *(const s16x8*)&w2t[(size_t)(nbase + t * 16 + l15) * HID + k0];
#pragma unroll
    for (int i = 0; i < 4; ++i)
#pragma unroll
      for (int j = 0; j < 4; ++j)
        acc[i][j] = __builtin_amdgcn_mfma_f32_16x16x32_bf16(af[i], bf[j], acc[i][j], 0, 0, 0);
  }
  float ebv[4];
#pragma unroll
  for (int t = 0; t < 4; ++t) ebv[t] = eb2[nbase + t * 16 + l15];
#pragma unroll
  for (int tr = 0; tr < 4; ++tr)
#pragma unroll
    for (int reg = 0; reg < 4; ++reg) {
      int row = rbase + tr * 16 + quad * 4 + reg;   // C/D: col=lane&15, row=quad*4+reg
#pragma unroll
      for (int tc = 0; tc < 4; ++tc) {
        int col = nbase + tc * 16 + l15;
        e8[(size_t)(e0 + row) * HID + col] = f2fp8(acc[tr][tc][reg] + ebv[tc]);
      }
    }
}

// ---------------- fused CSR-aggregate + conv MLP, 32-node tile ----------------
// phase A: DUAL-STREAM software SMT per wave. Each wave owns 8 nodes, split into
//   two independent streams (rows 0-3 and 4-7), each with its own r0-style
//   {A=fold, B=loaded, C=src-staged} pipeline and acc set, interleaved in one
//   loop: [stageC0+loadB0][stageC1+loadB1][foldA0][foldA1]. While one stream's
//   fold waits (vmcnt/flush-shfl chain) the other issues — halves exposed stall.
//   Control scalars readfirstlane'd -> SALU branches. e8 loads nontemporal.
__global__ void __launch_bounds__(256) k_conv_csr(
    const unsigned short* __restrict__ h16in, const unsigned char* __restrict__ e8,
    const int* __restrict__ src_s, const int* __restrict__ rowptr,
    const unsigned short* __restrict__ w1t, const float* __restrict__ b1,
    const unsigned short* __restrict__ w2t, const float* __restrict__ b2,
    unsigned short* __restrict__ h16out, int nN) {
  __shared__ __attribute__((aligned(16))) unsigned short zs[32 * LDP];
  __shared__ int rpS[4][12];
  int tid = threadIdx.x;
  int n0 = blockIdx.x * 32;
  int wave = tid >> 6, lane = tid & 63;
  int l15 = lane & 15, quad = lane >> 4;
  int c16 = l15 * 8;
  int wbase = wave * 8;
  // ---------- phase A ----------
  {
    int nodeBase = n0 + wbase;
    int nCnt = nN - nodeBase; if (nCnt > 8) nCnt = 8; if (nCnt < 0) nCnt = 0;
    // stage own 8 node rows into zs (2 x uint4 per lane)
#pragma unroll
    for (int i = 0; i < 2; ++i) {
      int r = i * 4 + quad;
      int n = nodeBase + r; if (n > nN - 1) n = nN - 1;
      *(uint4*)&zs[(wbase + r) * LDP + c16] =
          *(const uint4*)&h16in[(size_t)n * HID + c16];
    }
    if (lane < 9) {
      int i = (lane < nCnt) ? lane : nCnt;
      rpS[wave][lane] = (nCnt > 0) ? rowptr[nodeBase + i] : 0;
    }
    if (nCnt > 0) {
      const int* RP0 = &rpS[wave][0];
      const int* RP1 = &rpS[wave][4];
      float ac0[8], ac1[8];
#pragma unroll
      for (int j = 0; j < 8; ++j) { ac0[j] = 0.f; ac1[j] = 0.f; }

#define SINIT(GB, RE, NI, GE, RP)                                          \
      GB = __builtin_amdgcn_readfirstlane(RP[0]);                          \
      GE = __builtin_amdgcn_readfirstlane(RP[4]);                          \
      NI = 0;                                                              \
      while (NI < 4 && __builtin_amdgcn_readfirstlane(RP[NI + 1]) <= GB) ++NI; \
      RE = (NI < 4) ? __builtin_amdgcn_readfirstlane(RP[NI + 1]) : GB;

#define PS(EIX, SV, V, L, NIS, GB, RE, NI, RP)                             \
      { int gq = GB + quad;                                                \
        EIX = (gq < RE) ? gq : (RE - 1);                                   \
        V = (gq < RE);                                                     \
        L = (GB + 4 >= RE);                                                \
        NIS = NI;                                                          \
        SV = src_s[EIX];                                                   \
        GB = (GB + 4 < RE) ? (GB + 4) : RE;                                \
        if (GB >= RE) {                                                    \
          while (NI < 4 && __builtin_amdgcn_readfirstlane(RP[NI + 1]) <= GB) ++NI; \
          if (NI < 4) RE = __builtin_amdgcn_readfirstlane(RP[NI + 1]);     \
        } }

#define PEH(EV, HV, EIX, SV)                                               \
      { EV = __builtin_nontemporal_load(                                   \
            (const unsigned long long*)&e8[(size_t)(EIX) * HID + c16]);    \
        HV = *(const uint4*)&h16in[(size_t)(SV) * HID + c16]; }

#define FOLDX(ACC, EV, HV, V, L, NIS, RB)                                  \
      { if (V) {                                                           \
          unsigned int e0w = (unsigned int)(EV);                           \
          unsigned int e1w = (unsigned int)((EV) >> 32);                   \
          const unsigned int* hw = (const unsigned int*)&(HV);             \
          f32x2 pa = __builtin_amdgcn_cvt_pk_f32_fp8(e0w, false);          \
          f32x2 pb = __builtin_amdgcn_cvt_pk_f32_fp8(e0w, true);           \
          f32x2 pc = __builtin_amdgcn_cvt_pk_f32_fp8(e1w, false);          \
          f32x2 pd = __builtin_amdgcn_cvt_pk_f32_fp8(e1w, true);           \
          ACC[0] += fmaxf(asf(hw[0] << 16) + pa[0], 0.f);                  \
          ACC[1] += fmaxf(asf(hw[0] & 0xffff0000u) + pa[1], 0.f);          \
          ACC[2] += fmaxf(asf(hw[1] << 16) + pb[0], 0.f);                  \
          ACC[3] += fmaxf(asf(hw[1] & 0xffff0000u) + pb[1], 0.f);          \
          ACC[4] += fmaxf(asf(hw[2] << 16) + pc[0], 0.f);                  \
          ACC[5] += fmaxf(asf(hw[2] & 0xffff0000u) + pc[1], 0.f);          \
          ACC[6] += fmaxf(asf(hw[3] << 16) + pd[0], 0.f);                  \
          ACC[7] += fmaxf(asf(hw[3] & 0xffff0000u) + pd[1], 0.f);          \
        }                                                                  \
        if (L) {                                                           \
          _Pragma("unroll")                                                \
          for (int j = 0; j < 8; ++j) {                                    \
            ACC[j] += __shfl_xor(ACC[j], 16);                              \
            ACC[j] += __shfl_xor(ACC[j], 32);                              \
          }                                                                \
          if (quad == 0) {                                                 \
            int zr = ((RB) + (NIS)) * LDP + c16;                           \
            uint4 z = *(const uint4*)&zs[zr];                              \
            unsigned int* zw = (unsigned int*)&z;                          \
            _Pragma("unroll")                                              \
            for (int j = 0; j < 4; ++j) {                                  \
              float z0 = asf(zw[j] << 16) + ACC[2 * j];                    \
              float z1 = asf(zw[j] & 0xffff0000u) + ACC[2 * j + 1];        \
              zw[j] = (unsigned int)f2bf(z0) |                             \
                      ((unsigned int)f2bf(z1) << 16);                      \
            }                                                              \
            *(uint4*)&zs[zr] = z;                                          \
          }                                                                \
          _Pragma("unroll")                                                \
          for (int j = 0; j < 8; ++j) ACC[j] = 0.f;                        \
        } }

      int gb0, re0, ni0, gE0, gb1, re1, ni1, gE1;
      SINIT(gb0, re0, ni0, gE0, RP0)
      SINIT(gb1, re1, ni1, gE1, RP1)
      bool aA0 = false, aB0 = false, aA1 = false, aB1 = false;
      bool vA0 = false, vB0 = false, lA0 = false, lB0 = false;
      bool vA1 = false, vB1 = false, lA1 = false, lB1 = false;
      int exA0 = 0, exB0 = 0, svA0 = 0, svB0 = 0, niA0 = 0, niB0 = 0;
      int exA1 = 0, exB1 = 0, svA1 = 0, svB1 = 0, niA1 = 0, niB1 = 0;
      unsigned long long evA0 = 0, evB0 = 0, evA1 = 0, evB1 = 0;
      uint4 hvA0 = {0,0,0,0}, hvB0 = {0,0,0,0}, hvA1 = {0,0,0,0}, hvB1 = {0,0,0,0};
      if (gb0 < gE0) { PS(exA0, svA0, vA0, lA0, niA0, gb0, re0, ni0, RP0) aA0 = true; }
      if (gb0 < gE0) { PS(exB0, svB0, vB0, lB0, niB0, gb0, re0, ni0, RP0) aB0 = true; }
      if (gb1 < gE1) { PS(exA1, svA1, vA1, lA1, niA1, gb1, re1, ni1, RP1) aA1 = true; }
      if (gb1 < gE1) { PS(exB1, svB1, vB1, lB1, niB1, gb1, re1, ni1, RP1) aB1 = true; }
      if (aA0) PEH(evA0, hvA0, exA0, svA0)
      if (aA1) PEH(evA1, hvA1, exA1, svA1)
      while (aA0 || aA1) {
        bool aC0 = false, aC1 = false;
        bool vC0 = false, lC0 = false, vC1 = false, lC1 = false;
        int exC0 = 0, svC0 = 0, niC0 = 0, exC1 = 0, svC1 = 0, niC1 = 0;
        if (aA0) {
          aC0 = (gb0 < gE0);
          if (aC0) PS(exC0, svC0, vC0, lC0, niC0, gb0, re0, ni0, RP0)
          if (aB0) PEH(evB0, hvB0, exB0, svB0)
        }
        if (aA1) {
          aC1 = (gb1 < gE1);
          if (aC1) PS(exC1, svC1, vC1, lC1, niC1, gb1, re1, ni1, RP1)
          if (aB1) PEH(evB1, hvB1, exB1, svB1)
        }
        if (aA0) {
          FOLDX(ac0, evA0, hvA0, vA0, lA0, niA0, wbase)
          aA0 = aB0; evA0 = evB0; hvA0 = hvB0; vA0 = vB0; lA0 = lB0; niA0 = niB0;
          exA0 = exB0; svA0 = svB0;
          aB0 = aC0; exB0 = exC0; svB0 = svC0; vB0 = vC0; lB0 = lC0; niB0 = niC0;
        }
        if (aA1) {
          FOLDX(ac1, evA1, hvA1, vA1, lA1, niA1, wbase + 4)
          aA1 = aB1; evA1 = evB1; hvA1 = hvB1; vA1 = vB1; lA1 = lB1; niA1 = niB1;
          exA1 = exB1; svA1 = svB1;
          aB1 = aC1; exB1 = exC1; svB1 = svC1; vB1 = vC1; lB1 = lC1; niB1 = niC1;
        }
      }
#undef SINIT
#undef PS
#undef PEH
#undef FOLDX
    }
  }
  __syncthreads();
  // ---------- phase B: z @ w1 + b1, relu -> zs ----------
  int rbase = (wave >> 1) * 16, nbase = (wave & 1) * 64;
  f32x4 acc[4];
#pragma unroll
  for (int j = 0; j < 4; ++j) acc[j] = (f32x4){0.f, 0.f, 0.f, 0.f};
  for (int kc = 0; kc < 4; ++kc) {
    int k0 = kc * 32 + quad * 8;
    s16x8 af, bf[4];
    af = *(const s16x8*)&zs[(rbase + l15) * LDP + k0];
#pragma unroll
    for (int t = 0; t < 4; ++t)
      bf[t] = *(const s16x8*)&w1t[(size_t)(nbase + t * 16 + l15) * HID + k0];
#pragma unroll
    for (int j = 0; j < 4; ++j)
      acc[j] = __builtin_amdgcn_mfma_f32_16x16x32_bf16(af, bf[j], acc[j], 0, 0, 0);
  }
  __syncthreads();
  {
    float bv[4];
#pragma unroll
    for (int t = 0; t < 4; ++t) bv[t] = b1[nbase + t * 16 + l15];
#pragma unroll
    for (int tc = 0; tc < 4; ++tc)
#pragma unroll
      for (int reg = 0; reg < 4; ++reg) {
        int row = rbase + quad * 4 + reg;
        int col = nbase + tc * 16 + l15;
        zs[row * LDP + col] = f2bf(fmaxf(acc[tc][reg] + bv[tc], 0.f));
      }
  }
  __syncthreads();
  // ---------- phase C: @ w2 + b2, relu -> h16out ----------
#pragma unroll
  for (int j = 0; j < 4; ++j) acc[j] = (f32x4){0.f, 0.f, 0.f, 0.f};
  for (int kc = 0; kc < 4; ++kc) {
    int k0 = kc * 32 + quad * 8;
    s16x8 af, bf[4];
    af = *(const s16x8*)&zs[(rbase + l15) * LDP + k0];
#pragma unroll
    for (int t = 0; t < 4; ++t)
      bf[t] = *(const s16x8*)&w2t[(size_t)(nbase + t * 16 + l15) * HID + k0];
#pragma unroll
    for (int j = 0; j < 4; ++j)
      acc[j] = __builtin_amdgcn_mfma_f32_16x16x32_bf16(af, bf[j], acc[j], 0, 0, 0);
  }
  {
    float bv[4];
#pragma unroll
    for (int t = 0; t < 4; ++t) bv[t] = b2[nbase + t * 16 + l15];
#pragma unroll
    for (int reg = 0; reg < 4; ++reg) {
      int grow = n0 + rbase + quad * 4 + reg;
      if (grow < nN) {
#pragma unroll
        for (int tc = 0; tc < 4; ++tc) {
          int col = nbase + tc * 16 + l15;
          h16out[(size_t)grow * HID + col] = f2bf(fmaxf(acc[tc][reg] + bv[tc], 0.f));
        }
      }
    }
  }
}

// ---------------- counts ----------------
__global__ void k_counts(const int* __restrict__ batch, int* __restrict__ cnts, int nN) {
  int i = blockIdx.x * blockDim.x + threadIdx.x;
  if (i < nN) atomicAdd(&cnts[batch[i]], 1);
}

// ---------------- segment-reduced pool (batch sorted) ----------------
__global__ void __launch_bounds__(256) k_pool2(
    const unsigned short* __restrict__ h16, const int* __restrict__ batch,
    float* __restrict__ g, int nN) {
  __shared__ int bL[128];
  int tid = threadIdx.x;
  int n0 = blockIdx.x * 128;
  if (tid < 128) {
    int n = n0 + tid;
    bL[tid] = (n < nN) ? batch[n] : -1;
  }
  __syncthreads();
  int half = tid >> 7, col = tid & 127;
  int rs = half * 64;
  int cur = -1;
  float s = 0.f;
  for (int r = rs; r < rs + 64; ++r) {
    int b = bL[r];
    float v = (b >= 0) ? bf2f((unsigned int)h16[(size_t)(n0 + r) * HID + col]) : 0.f;
    if (b != cur) {
      if (cur >= 0) atomicAdd(&g[(size_t)cur * HID + col], s);
      cur = b; s = v;
    } else s += v;
  }
  if (cur >= 0) atomicAdd(&g[(size_t)cur * HID + col], s);
}

// ---------------- heads ----------------
__global__ void __launch_bounds__(128) k_head(
    const float* __restrict__ g, const int* __restrict__ counts,
    const float* __restrict__ clw1, const float* __restrict__ clb1,
    const float* __restrict__ clw2, const float* __restrict__ clb2,
    const float* __restrict__ rw1, const float* __restrict__ rb1,
    const float* __restrict__ rw2, const float* __restrict__ rb2,
    float* __restrict__ out, int nG) {
  __shared__ float gs[HID];
  int b = blockIdx.x;
  int tid = threadIdx.x;
  float cnt = fmaxf((float)counts[b], 1.f);
  gs[tid] = g[b * HID + tid] / cnt;
  __syncthreads();
  int wave = tid >> 6, lane = tid & 63;
  const float* w1 = wave ? rw1 : clw1;
  const float* b1 = wave ? rb1 : clb1;
  const float* w2 = wave ? rw2 : clw2;
  const float* b2 = wave ? rb2 : clb2;
  float acc = b1[lane];
  for (int k = 0; k < HID; ++k) acc += gs[k] * w1[k * 64 + lane];
  acc = fmaxf(acc, 0.f) * w2[lane];
#pragma unroll
  for (int off = 32; off; off >>= 1) acc += __shfl_down(acc, off);
  if (lane == 0) out[wave * nG + b] = acc + b2[0];
}

extern "C" void kernel_launch(void* const* d_in, const int* in_sizes, int n_in,
                              void* d_out, int out_size, void* d_ws, size_t ws_size,
                              hipStream_t stream) {
  const float* x      = (const float*)d_in[0];
  const float* ea     = (const float*)d_in[1];
  const int*   eidx   = (const int*)d_in[2];
  const int*   batch  = (const int*)d_in[3];
  const float* node_w = (const float*)d_in[4];
  const float* node_b = (const float*)d_in[5];
  const float* ew1    = (const float*)d_in[6];
  const float* eb1    = (const float*)d_in[7];
  const float* ew2    = (const float*)d_in[8];
  const float* eb2    = (const float*)d_in[9];
  const float* cw1    = (const float*)d_in[10];
  const float* cb1    = (const float*)d_in[11];
  const float* cw2    = (const float*)d_in[12];
  const float* cb2    = (const float*)d_in[13];
  const float* clw1   = (const float*)d_in[14];
  const float* clb1   = (const float*)d_in[15];
  const float* clw2   = (const float*)d_in[16];
  const float* clb2   = (const float*)d_in[17];
  const float* rw1    = (const float*)d_in[18];
  const float* rb1    = (const float*)d_in[19];
  const float* rw2    = (const float*)d_in[20];
  const float* rb2    = (const float*)d_in[21];
  float* out = (float*)d_out;

  int nN = in_sizes[3];        // 100000
  int nE = in_sizes[2] / 2;    // 640000 (divisible by 128)
  int nG = out_size / 2;       // 2048
  const int* src = eidx;
  const int* dst = eidx + nE;

  int NB = (nN + 255) / 256;
  int bins = NB * 256;

  // ---- workspace (~140 MB) ----
  size_t hN = (size_t)nN * HID;
  size_t gN = (size_t)nG * HID;
  float* g    = (float*)d_ws;                       // gN
  int*   cnts = (int*)(g + gN);                     // nG
  unsigned short* wT   = (unsigned short*)(cnts + nG);  // 7*16384
  unsigned short* h16a = wT + 7 * 16384;            // hN
  unsigned short* h16b = h16a + hN;                 // hN
  int* deg    = (int*)(h16b + hN);                  // bins
  int* cursor = deg + bins;                         // bins
  int* rowptr = cursor + bins;                      // bins
  int* bsum   = rowptr + bins;                      // 512
  int* bsumx  = bsum + 512;                         // 512
  int* src_s  = bsumx + 512;                        // nE
  int* esort  = src_s + nE;                         // nE
  unsigned char* e8 = (unsigned char*)(esort + nE); // nE*128 fp8

  // ---- counting sort of edges by dst (builds CSR rowptr + permutation) ----
  k_zero4<<<(int)((bins / 4 + 255) / 256), 256, 0, stream>>>((float4*)deg, bins / 4);
  k_hist<<<(nE + 255) / 256, 256, 0, stream>>>(dst, deg, nE);
  k_scanA<<<NB, 256, 0, stream>>>(deg, bsum);
  k_scanB<<<1, 512, 0, stream>>>(bsum, bsumx, NB);
  k_scanC<<<NB, 256, 0, stream>>>(deg, bsumx, cursor, rowptr);
  k_scatter<<<(nE + 255) / 256, 256, 0, stream>>>(src, dst, cursor, src_s, esort, nE);

  k_prep_w<<<(7 * 16384 + 255) / 256, 256, 0, stream>>>(ew2, cw1, cw2, wT);
  k_edge_gemm<<<nE / 128, 256, 0, stream>>>(ea, esort, ew1, eb1, wT, eb2, e8, nE);
  k_node_enc<<<(nN * HID + 255) / 256, 256, 0, stream>>>(x, node_w, node_b, h16a, nN);

  // ping-pong: A->B, B->A, A->B  (final in h16b)
  unsigned short* hin  = h16a;
  unsigned short* hout = h16b;
  for (int l = 0; l < 3; ++l) {
    k_conv_csr<<<(nN + 31) / 32, 256, 0, stream>>>(
        hin, e8, src_s, rowptr,
        wT + (size_t)(1 + l) * 16384, cb1 + (size_t)l * HID,
        wT + (size_t)(4 + l) * 16384, cb2 + (size_t)l * HID, hout, nN);
    unsigned short* t = hin; hin = hout; hout = t;
  }

  k_zero4<<<(int)(((gN + nG) / 4 + 255) / 256), 256, 0, stream>>>((float4*)g, (gN + nG) / 4);
  k_counts<<<(nN + 255) / 256, 256, 0, stream>>>(batch, cnts, nN);
  k_pool2<<<(nN + 127) / 128, 256, 0, stream>>>(hin, batch, g, nN);
  k_head<<<nG, 128, 0, stream>>>(g, cnts, clw1, clb1, clw2, clb2,
                                 rw1, rb1, rw2, rb2, out, nG);
}

// Round 9
// 608.990 us; speedup vs baseline: 1.0597x; 1.0597x over previous
//
#include <hip/hip_runtime.h>

#define HID 128
#define LDP 136   // padded LDS row stride in bf16 elems (272 B)

typedef short s16x8 __attribute__((ext_vector_type(8)));
typedef float f32x4 __attribute__((ext_vector_type(4)));
typedef float f32x2 __attribute__((ext_vector_type(2)));

__device__ __forceinline__ float bf2f(unsigned int u) {
  union { unsigned int i; float f; } v; v.i = u << 16; return v.f;
}
__device__ __forceinline__ float asf(unsigned int u) {
  union { unsigned int i; float f; } v; v.i = u; return v.f;
}
__device__ __forceinline__ unsigned short f2bf(float f) {
  union { float f; unsigned int i; } v; v.f = f;
  unsigned int r = v.i + 0x7fffu + ((v.i >> 16) & 1u);
  return (unsigned short)(r >> 16);
}
// f32 -> fp8 e4m3 byte (RNE, via HW cvt)
__device__ __forceinline__ unsigned char f2fp8(float f) {
  unsigned int p = __builtin_amdgcn_cvt_pk_fp8_f32(f, f, 0u, false);
  return (unsigned char)(p & 0xffu);
}

// ---------------- fused init: zero(deg) | zero(g,cnts,galloc) | prep_w | node_enc ----------------
__global__ void __launch_bounds__(256) k_init(
    float4* __restrict__ zd, int nzd4, float4* __restrict__ zg, int nzg4,
    const float* __restrict__ ew2, const float* __restrict__ cw1,
    const float* __restrict__ cw2, unsigned short* __restrict__ wT,
    const float* __restrict__ x, const float* __restrict__ nw,
    const float* __restrict__ nb, unsigned short* __restrict__ h16, int nN,
    int bZD, int bZG, int bPW) {
  int bid = blockIdx.x, tid = threadIdx.x;
  if (bid < bZD) {
    int i = bid * 256 + tid;
    if (i < nzd4) zd[i] = (float4){0.f, 0.f, 0.f, 0.f};
    return;
  }
  bid -= bZD;
  if (bid < bZG) {
    int i = bid * 256 + tid;
    if (i < nzg4) zg[i] = (float4){0.f, 0.f, 0.f, 0.f};
    return;
  }
  bid -= bZG;
  if (bid < bPW) {            // transpose weights to bf16 (7*16384 == bPW*256)
    int idx = bid * 256 + tid;
    int m = idx >> 14, i = idx & 16383;
    int n = i >> 7, k = i & 127;
    const float* s = (m == 0) ? ew2 : (m <= 3 ? cw1 + (size_t)(m - 1) * 16384
                                              : cw2 + (size_t)(m - 4) * 16384);
    wT[idx] = f2bf(s[k * 128 + n]);
    return;
  }
  bid -= bPW;
  int idx = bid * 256 + tid;  // node encoder
  if (idx < nN * HID) {
    int i = idx >> 7, j = idx & 127;
    float acc = nb[j];
    const float* xr = x + (size_t)i * 7;
#pragma unroll
    for (int k = 0; k < 7; ++k) acc += xr[k] * nw[k * HID + j];
    h16[idx] = f2bf(acc);
  }
}

// ---------------- histogram ----------------
__global__ void k_hist(const int* __restrict__ dst, int* __restrict__ deg, int nE) {
  int e = blockIdx.x * blockDim.x + threadIdx.x;
  if (e < nE) atomicAdd(&deg[dst[e]], 1);
}

// ---------------- single-kernel scan: local block scan + atomic base allocation ----------------
// CSR block bases are assigned in arbitrary (atomic) order; per-node ranges within a
// 256-node block are contiguous, which is all conv needs (8-node groups are aligned).
// rpe[n] = rowptr[n] + deg[n] gives the per-node end (valid across block boundaries).
__global__ void __launch_bounds__(256) k_scan(
    const int* __restrict__ deg, int* __restrict__ galloc,
    int* __restrict__ cursor, int* __restrict__ rowptr, int* __restrict__ rpe) {
  __shared__ int ss[256];
  __shared__ int sbase;
  int t = threadIdx.x, i = blockIdx.x * 256 + t;
  int v = deg[i];
  ss[t] = v;
  __syncthreads();
  for (int off = 1; off < 256; off <<= 1) {
    int a = (t >= off) ? ss[t - off] : 0;
    __syncthreads();
    ss[t] += a;
    __syncthreads();
  }
  if (t == 255) sbase = atomicAdd(galloc, ss[255]);
  __syncthreads();
  int ex = ss[t] - v + sbase;
  cursor[i] = ex;
  rowptr[i] = ex;
  rpe[i] = ex + v;
}

// permute: only src and edge id (8 B random writes; ea gathered later from L3)
__global__ void k_scatter(const int* __restrict__ src, const int* __restrict__ dst,
                          int* __restrict__ cursor,
                          int* __restrict__ src_s, int* __restrict__ esort, int nE) {
  int e = blockIdx.x * blockDim.x + threadIdx.x;
  if (e >= nE) return;
  int d = dst[e];
  int pos = atomicAdd(&cursor[d], 1);
  src_s[pos] = src[e];
  esort[pos] = e;
}

// ---------------- one-time edge encoder GEMM -> e8 (fp8, sorted order) ----------------
// gathers ea rows through esort (ea is L3-resident)
__global__ void __launch_bounds__(256) k_edge_gemm(
    const float* __restrict__ ea, const int* __restrict__ esort,
    const float* __restrict__ ew1, const float* __restrict__ eb1,
    const unsigned short* __restrict__ w2t, const float* __restrict__ eb2,
    unsigned char* __restrict__ e8, int nE) {
  __shared__ __attribute__((aligned(16))) unsigned short ts1[128 * LDP];
  __shared__ float eaL[384];
  __shared__ int esL[128];
  int tid = threadIdx.x;
  int e0 = blockIdx.x * 128;                      // nE % 128 == 0
  if (tid < 128) esL[tid] = esort[e0 + tid];
  __syncthreads();
  for (int i = tid; i < 384; i += 256) {
    int r = i / 3, c = i - r * 3;
    eaL[i] = ea[(size_t)esL[r] * 3 + c];
  }
  __syncthreads();
  {
    int j = tid & 127, r0 = (tid >> 7) * 64;
    float wa = ew1[j], wb = ew1[HID + j], wc = ew1[2 * HID + j], bj = eb1[j];
    for (int r = r0; r < r0 + 64; ++r) {
      float a = bj + eaL[r * 3] * wa + eaL[r * 3 + 1] * wb + eaL[r * 3 + 2] * wc;
      ts1[r * LDP + j] = f2bf(fmaxf(a, 0.f));
    }
  }
  __syncthreads();
  int wave = tid >> 6, lane = tid & 63;
  int l15 = lane & 15, quad = lane >> 4;
  int rbase = (wave >> 1) * 64, nbase = (wave & 1) * 64;
  f32x4 acc[4][4];
#pragma unroll
  for (int i = 0; i < 4; ++i)
#pragma unroll
    for (int j = 0; j < 4; ++j) acc[i][j] = (f32x4){0.f, 0.f, 0.f, 0.f};
  for (int kc = 0; kc < 4; ++kc) {
    int k0 = kc * 32 + quad * 8;
    s16x8 af[4], bf[4];
#pragma unroll
    for (int t = 0; t < 4; ++t)
      af[t] = *(const s16x8*)&ts1[(rbase + t * 16 + l15) * LDP + k0];
#pragma unroll
    for (int t = 0; t < 4; ++t)
      bf[t] = *(const s16x8*)&w2t[(size_t)(nbase + t * 16 + l15) * HID + k0];
#pragma unroll
    for (int i = 0; i < 4; ++i)
#pragma unroll
      for (int j = 0; j < 4; ++j)
        acc[i][j] = __builtin_amdgcn_mfma_f32_16x16x32_bf16(af[i], bf[j], acc[i][j], 0, 0, 0);
  }
  float ebv[4];
#pragma unroll
  for (int t = 0; t < 4; ++t) ebv[t] = eb2[nbase + t * 16 + l15];
#pragma unroll
  for (int tr = 0; tr < 4; ++tr)
#pragma unroll
    for (int reg = 0; reg < 4; ++reg) {
      int row = rbase + tr * 16 + quad * 4 + reg;   // C/D: col=lane&15, row=quad*4+reg
#pragma unroll
      for (int tc = 0; tc < 4; ++tc) {
        int col = nbase + tc * 16 + l15;
        e8[(size_t)(e0 + row) * HID + col] = f2fp8(acc[tr][tc][reg] + ebv[tc]);
      }
    }
}

// ---------------- fused CSR-aggregate + conv MLP, 32-node tile (round-0 structure) ----------------
// phase A (16B/lane, fp8 e): node-aligned groups of 4 edges; quad q owns edge
//   gb+q; lane covers 8 cols: e via uint2 (8 B fp8), h via uint4 (16 B bf16).
//   fp32 per-quad partials; node-end: shfl_xor butterfly + quad-0 b128 RMW.
//   rpS[8] comes from rpe (per-node end) so CSR block bases may be jumbled.
__global__ void __launch_bounds__(256) k_conv_csr(
    const unsigned short* __restrict__ h16in, const unsigned char* __restrict__ e8,
    const int* __restrict__ src_s, const int* __restrict__ rowptr,
    const int* __restrict__ rpe,
    const unsigned short* __restrict__ w1t, const float* __restrict__ b1,
    const unsigned short* __restrict__ w2t, const float* __restrict__ b2,
    unsigned short* __restrict__ h16out, int nN) {
  __shared__ __attribute__((aligned(16))) unsigned short zs[32 * LDP];
  __shared__ int rpS[4][12];
  int tid = threadIdx.x;
  int n0 = blockIdx.x * 32;
  int wave = tid >> 6, lane = tid & 63;
  int l15 = lane & 15, quad = lane >> 4;
  // phase A
  {
    int c16 = l15 * 8;                  // col base (8 cols per lane)
    int c2 = lane * 2;
    int wbase = wave * 8;
    int nodeBase = n0 + wbase;
    int nCnt = nN - nodeBase; if (nCnt > 8) nCnt = 8; if (nCnt < 0) nCnt = 0;
#pragma unroll
    for (int i = 0; i < 8; ++i) {
      int n = nodeBase + i;
      unsigned int hv = 0u;
      if (n < nN) hv = *(const unsigned int*)&h16in[(size_t)n * HID + c2];
      *(unsigned int*)&zs[(wbase + i) * LDP + c2] = hv;
    }
    if (lane < 8) {
      int i = (lane < nCnt) ? lane : (nCnt > 0 ? nCnt - 1 : 0);
      rpS[wave][lane] = (nCnt > 0) ? rowptr[nodeBase + i] : 0;
    }
    if (lane == 8) rpS[wave][8] = (nCnt > 0) ? rpe[nodeBase + nCnt - 1] : 0;
    if (nCnt > 0) {
      int gb = rpS[wave][0];
      int gEnd = rpS[wave][8];
      int ni = 0;
      while (ni < 8 && rpS[wave][ni + 1] <= gb) ++ni;
      int re = (ni < 8) ? rpS[wave][ni + 1] : gb;
      float acc[8];
#pragma unroll
      for (int j = 0; j < 8; ++j) acc[j] = 0.f;

      int eixA = 0, eixB = 0, eixC = 0, svA = 0, svB = 0, svC = 0;
      int niA = 0, niB = 0, niC = 0;
      bool vA = false, vB = false, vC = false, lA = false, lB = false, lC = false;
      uint2 evA, evB;
      uint4 hvA, hvB;
      bool aA = false, aB = false, aC = false;

#define PS(eix, sv, v, l, nis)                                   \
  { int gq = gb + quad;                                          \
    eix = (gq < re) ? gq : (re - 1);                             \
    v = (gq < re);                                               \
    l = (gb + 4 >= re);                                          \
    nis = ni;                                                    \
    sv = src_s[eix];                                             \
    gb = (gb + 4 < re) ? (gb + 4) : re;                          \
    if (gb >= re) {                                              \
      while (ni < 8 && rpS[wave][ni + 1] <= gb) ++ni;            \
      if (ni < 8) re = rpS[wave][ni + 1];                        \
    } }
#define PEH(ev, hv, eix, sv)                                     \
  { ev = *(const uint2*)&e8[(size_t)eix * HID + c16];            \
    hv = *(const uint4*)&h16in[(size_t)sv * HID + c16]; }
#define FOLDX(ev, hv, v, l, nis)                                 \
  { const unsigned int* ew = (const unsigned int*)&ev;           \
    const unsigned int* hw = (const unsigned int*)&hv;           \
    if (v) {                                                     \
      _Pragma("unroll")                                          \
      for (int j = 0; j < 2; ++j) {                              \
        f32x2 pa = __builtin_amdgcn_cvt_pk_f32_fp8(ew[j], false); \
        f32x2 pb = __builtin_amdgcn_cvt_pk_f32_fp8(ew[j], true);  \
        acc[4*j+0] += fmaxf(asf(hw[2*j] << 16) + pa[0], 0.f);    \
        acc[4*j+1] += fmaxf(asf(hw[2*j] & 0xffff0000u) + pa[1], 0.f); \
        acc[4*j+2] += fmaxf(asf(hw[2*j+1] << 16) + pb[0], 0.f);  \
        acc[4*j+3] += fmaxf(asf(hw[2*j+1] & 0xffff0000u) + pb[1], 0.f); \
      }                                                          \
    }                                                            \
    if (l) {                                                     \
      _Pragma("unroll")                                          \
      for (int j = 0; j < 8; ++j) {                              \
        acc[j] += __shfl_xor(acc[j], 16);                        \
        acc[j] += __shfl_xor(acc[j], 32);                        \
      }                                                          \
      if (quad == 0) {                                           \
        int row = wbase + nis;                                   \
        uint4 z = *(const uint4*)&zs[row * LDP + c16];           \
        unsigned int* zw = (unsigned int*)&z;                    \
        _Pragma("unroll")                                        \
        for (int j = 0; j < 4; ++j) {                            \
          float z0 = asf(zw[j] << 16) + acc[2*j];                \
          float z1 = asf(zw[j] & 0xffff0000u) + acc[2*j+1];      \
          zw[j] = (unsigned int)f2bf(z0) | ((unsigned int)f2bf(z1) << 16); \
        }                                                        \
        *(uint4*)&zs[row * LDP + c16] = z;                       \
      }                                                          \
      _Pragma("unroll")                                          \
      for (int j = 0; j < 8; ++j) acc[j] = 0.f;                  \
    } }

      if (gb < gEnd) { PS(eixA, svA, vA, lA, niA) aA = true; }
      if (gb < gEnd) { PS(eixB, svB, vB, lB, niB) aB = true; }
      if (aA) PEH(evA, hvA, eixA, svA)
      while (aA) {
        aC = (gb < gEnd);
        if (aC) PS(eixC, svC, vC, lC, niC)
        if (aB) PEH(evB, hvB, eixB, svB)
        FOLDX(evA, hvA, vA, lA, niA)
        aA = aB; evA = evB; hvA = hvB; vA = vB; lA = lB; niA = niB; eixA = eixB; svA = svB;
        aB = aC; eixB = eixC; svB = svC; vB = vC; lB = lC; niB = niC;
      }
#undef PS
#undef PEH
#undef FOLDX
    }
  }
  __syncthreads();
  int rbase = (wave >> 1) * 16, nbase = (wave & 1) * 64;
  f32x4 acc[4];
#pragma unroll
  for (int j = 0; j < 4; ++j) acc[j] = (f32x4){0.f, 0.f, 0.f, 0.f};
  for (int kc = 0; kc < 4; ++kc) {
    int k0 = kc * 32 + quad * 8;
    s16x8 af, bf[4];
    af = *(const s16x8*)&zs[(rbase + l15) * LDP + k0];
#pragma unroll
    for (int t = 0; t < 4; ++t)
      bf[t] = *(const s16x8*)&w1t[(size_t)(nbase + t * 16 + l15) * HID + k0];
#pragma unroll
    for (int j = 0; j < 4; ++j)
      acc[j] = __builtin_amdgcn_mfma_f32_16x16x32_bf16(af, bf[j], acc[j], 0, 0, 0);
  }
  __syncthreads();
  {
    float bv[4];
#pragma unroll
    for (int t = 0; t < 4; ++t) bv[t] = b1[nbase + t * 16 + l15];
#pragma unroll
    for (int tc = 0; tc < 4; ++tc)
#pragma unroll
      for (int reg = 0; reg < 4; ++reg) {
        int row = rbase + quad * 4 + reg;
        int col = nbase + tc * 16 + l15;
        zs[row * LDP + col] = f2bf(fmaxf(acc[tc][reg] + bv[tc], 0.f));
      }
  }
  __syncthreads();
#pragma unroll
  for (int j = 0; j < 4; ++j) acc[j] = (f32x4){0.f, 0.f, 0.f, 0.f};
  for (int kc = 0; kc < 4; ++kc) {
    int k0 = kc * 32 + quad * 8;
    s16x8 af, bf[4];
    af = *(const s16x8*)&zs[(rbase + l15) * LDP + k0];
#pragma unroll
    for (int t = 0; t < 4; ++t)
      bf[t] = *(const s16x8*)&w2t[(size_t)(nbase + t * 16 + l15) * HID + k0];
#pragma unroll
    for (int j = 0; j < 4; ++j)
      acc[j] = __builtin_amdgcn_mfma_f32_16x16x32_bf16(af, bf[j], acc[j], 0, 0, 0);
  }
  {
    float bv[4];
#pragma unroll
    for (int t = 0; t < 4; ++t) bv[t] = b2[nbase + t * 16 + l15];
#pragma unroll
    for (int reg = 0; reg < 4; ++reg) {
      int grow = n0 + rbase + quad * 4 + reg;
      if (grow < nN) {
#pragma unroll
        for (int tc = 0; tc < 4; ++tc) {
          int col = nbase + tc * 16 + l15;
          h16out[(size_t)grow * HID + col] = f2bf(fmaxf(acc[tc][reg] + bv[tc], 0.f));
        }
      }
    }
  }
}

// ---------------- segment-reduced pool + graph counts (batch sorted) ----------------
__global__ void __launch_bounds__(256) k_pool2(
    const unsigned short* __restrict__ h16, const int* __restrict__ batch,
    float* __restrict__ g, int* __restrict__ cnts, int nN) {
  __shared__ int bL[128];
  int tid = threadIdx.x;
  int n0 = blockIdx.x * 128;
  if (tid < 128) {
    int n = n0 + tid;
    bL[tid] = (n < nN) ? batch[n] : -1;
  }
  __syncthreads();
  int half = tid >> 7, col = tid & 127;
  int rs = half * 64;
  int cur = -1, rl = 0;
  float s = 0.f;
  for (int r = rs; r < rs + 64; ++r) {
    int b = bL[r];
    float v = (b >= 0) ? bf2f((unsigned int)h16[(size_t)(n0 + r) * HID + col]) : 0.f;
    if (b != cur) {
      if (cur >= 0) {
        atomicAdd(&g[(size_t)cur * HID + col], s);
        if (col == 0) atomicAdd(&cnts[cur], rl);
      }
      cur = b; s = v; rl = 1;
    } else { s += v; ++rl; }
  }
  if (cur >= 0) {
    atomicAdd(&g[(size_t)cur * HID + col], s);
    if (col == 0) atomicAdd(&cnts[cur], rl);
  }
}

// ---------------- heads ----------------
__global__ void __launch_bounds__(128) k_head(
    const float* __restrict__ g, const int* __restrict__ counts,
    const float* __restrict__ clw1, const float* __restrict__ clb1,
    const float* __restrict__ clw2, const float* __restrict__ clb2,
    const float* __restrict__ rw1, const float* __restrict__ rb1,
    const float* __restrict__ rw2, const float* __restrict__ rb2,
    float* __restrict__ out, int nG) {
  __shared__ float gs[HID];
  int b = blockIdx.x;
  int tid = threadIdx.x;
  float cnt = fmaxf((float)counts[b], 1.f);
  gs[tid] = g[b * HID + tid] / cnt;
  __syncthreads();
  int wave = tid >> 6, lane = tid & 63;
  const float* w1 = wave ? rw1 : clw1;
  const float* b1 = wave ? rb1 : clb1;
  const float* w2 = wave ? rw2 : clw2;
  const float* b2 = wave ? rb2 : clb2;
  float acc = b1[lane];
  for (int k = 0; k < HID; ++k) acc += gs[k] * w1[k * 64 + lane];
  acc = fmaxf(acc, 0.f) * w2[lane];
#pragma unroll
  for (int off = 32; off; off >>= 1) acc += __shfl_down(acc, off);
  if (lane == 0) out[wave * nG + b] = acc + b2[0];
}

extern "C" void kernel_launch(void* const* d_in, const int* in_sizes, int n_in,
                              void* d_out, int out_size, void* d_ws, size_t ws_size,
                              hipStream_t stream) {
  const float* x      = (const float*)d_in[0];
  const float* ea     = (const float*)d_in[1];
  const int*   eidx   = (const int*)d_in[2];
  const int*   batch  = (const int*)d_in[3];
  const float* node_w = (const float*)d_in[4];
  const float* node_b = (const float*)d_in[5];
  const float* ew1    = (const float*)d_in[6];
  const float* eb1    = (const float*)d_in[7];
  const float* ew2    = (const float*)d_in[8];
  const float* eb2    = (const float*)d_in[9];
  const float* cw1    = (const float*)d_in[10];
  const float* cb1    = (const float*)d_in[11];
  const float* cw2    = (const float*)d_in[12];
  const float* cb2    = (const float*)d_in[13];
  const float* clw1   = (const float*)d_in[14];
  const float* clb1   = (const float*)d_in[15];
  const float* clw2   = (const float*)d_in[16];
  const float* clb2   = (const float*)d_in[17];
  const float* rw1    = (const float*)d_in[18];
  const float* rb1    = (const float*)d_in[19];
  const float* rw2    = (const float*)d_in[20];
  const float* rb2    = (const float*)d_in[21];
  float* out = (float*)d_out;

  int nN = in_sizes[3];        // 100000
  int nE = in_sizes[2] / 2;    // 640000 (divisible by 128)
  int nG = out_size / 2;       // 2048
  const int* src = eidx;
  const int* dst = eidx + nE;

  int NB = (nN + 255) / 256;
  int bins = NB * 256;

  // ---- workspace (~141 MB) ----
  size_t hN = (size_t)nN * HID;
  size_t gN = (size_t)nG * HID;
  float* g      = (float*)d_ws;                     // gN
  int*   cnts   = (int*)(g + gN);                   // nG
  int*   galloc = cnts + nG;                        // 4 (zeroed with g/cnts)
  unsigned short* wT   = (unsigned short*)(galloc + 4); // 7*16384
  unsigned short* h16a = wT + 7 * 16384;            // hN
  unsigned short* h16b = h16a + hN;                 // hN
  int* deg    = (int*)(h16b + hN);                  // bins
  int* cursor = deg + bins;                         // bins
  int* rowptr = cursor + bins;                      // bins
  int* rpe    = rowptr + bins;                      // bins
  int* src_s  = rpe + bins;                         // nE
  int* esort  = src_s + nE;                         // nE
  unsigned char* e8 = (unsigned char*)(esort + nE); // nE*128 fp8

  int nzd4 = bins / 4;                              // deg zero, float4 units
  int nzg4 = (int)((gN + nG + 4) / 4);              // g + cnts + galloc
  int bZD = (nzd4 + 255) / 256;
  int bZG = (nzg4 + 255) / 256;
  int bPW = (7 * 16384) / 256;                      // 448 exact
  int bNE = (nN * HID + 255) / 256;

  k_init<<<bZD + bZG + bPW + bNE, 256, 0, stream>>>(
      (float4*)deg, nzd4, (float4*)g, nzg4,
      ew2, cw1, cw2, wT, x, node_w, node_b, h16a, nN, bZD, bZG, bPW);
  k_hist<<<(nE + 255) / 256, 256, 0, stream>>>(dst, deg, nE);
  k_scan<<<NB, 256, 0, stream>>>(deg, galloc, cursor, rowptr, rpe);
  k_scatter<<<(nE + 255) / 256, 256, 0, stream>>>(src, dst, cursor, src_s, esort, nE);
  k_edge_gemm<<<nE / 128, 256, 0, stream>>>(ea, esort, ew1, eb1, wT, eb2, e8, nE);

  // ping-pong: A->B, B->A, A->B  (final in h16b)
  unsigned short* hin  = h16a;
  unsigned short* hout = h16b;
  for (int l = 0; l < 3; ++l) {
    k_conv_csr<<<(nN + 31) / 32, 256, 0, stream>>>(
        hin, e8, src_s, rowptr, rpe,
        wT + (size_t)(1 + l) * 16384, cb1 + (size_t)l * HID,
        wT + (size_t)(4 + l) * 16384, cb2 + (size_t)l * HID, hout, nN);
    unsigned short* t = hin; hin = hout; hout = t;
  }

  k_pool2<<<(nN + 127) / 128, 256, 0, stream>>>(hin, batch, g, cnts, nN);
  k_head<<<nG, 128, 0, stream>>>(g, cnts, clw1, clb1, clw2, clb2,
                                 rw1, rb1, rw2, rb2, out, nG);
}

// Round 10
// 568.444 us; speedup vs baseline: 1.1353x; 1.0713x over previous
//
#include <hip/hip_runtime.h>

#define HID 128
#define LDP 136   // padded LDS row stride in bf16 elems (272 B)

typedef short s16x8 __attribute__((ext_vector_type(8)));
typedef float f32x4 __attribute__((ext_vector_type(4)));
typedef float f32x2 __attribute__((ext_vector_type(2)));

__device__ __forceinline__ float bf2f(unsigned int u) {
  union { unsigned int i; float f; } v; v.i = u << 16; return v.f;
}
__device__ __forceinline__ float asf(unsigned int u) {
  union { unsigned int i; float f; } v; v.i = u; return v.f;
}
__device__ __forceinline__ unsigned short f2bf(float f) {
  union { float f; unsigned int i; } v; v.f = f;
  unsigned int r = v.i + 0x7fffu + ((v.i >> 16) & 1u);
  return (unsigned short)(r >> 16);
}
// f32 -> fp8 e4m3 byte (RNE, via HW cvt)
__device__ __forceinline__ unsigned char f2fp8(float f) {
  unsigned int p = __builtin_amdgcn_cvt_pk_fp8_f32(f, f, 0u, false);
  return (unsigned char)(p & 0xffu);
}

// ---------------- fused init: zero(deg) | zero(g,cnts) | prep_w | node_enc ----------------
__global__ void __launch_bounds__(256) k_init(
    float4* __restrict__ zd, int nzd4, float4* __restrict__ zg, int nzg4,
    const float* __restrict__ ew2, const float* __restrict__ cw1,
    const float* __restrict__ cw2, unsigned short* __restrict__ wT,
    const float* __restrict__ x, const float* __restrict__ nw,
    const float* __restrict__ nb, unsigned short* __restrict__ h16, int nN,
    int bZD, int bZG, int bPW) {
  int bid = blockIdx.x, tid = threadIdx.x;
  if (bid < bZD) {
    int i = bid * 256 + tid;
    if (i < nzd4) zd[i] = (float4){0.f, 0.f, 0.f, 0.f};
    return;
  }
  bid -= bZD;
  if (bid < bZG) {
    int i = bid * 256 + tid;
    if (i < nzg4) zg[i] = (float4){0.f, 0.f, 0.f, 0.f};
    return;
  }
  bid -= bZG;
  if (bid < bPW) {            // transpose weights to bf16 (7*16384 == bPW*256)
    int idx = bid * 256 + tid;
    int m = idx >> 14, i = idx & 16383;
    int n = i >> 7, k = i & 127;
    const float* s = (m == 0) ? ew2 : (m <= 3 ? cw1 + (size_t)(m - 1) * 16384
                                              : cw2 + (size_t)(m - 4) * 16384);
    wT[idx] = f2bf(s[k * 128 + n]);
    return;
  }
  bid -= bPW;
  int idx = bid * 256 + tid;  // node encoder
  if (idx < nN * HID) {
    int i = idx >> 7, j = idx & 127;
    float acc = nb[j];
    const float* xr = x + (size_t)i * 7;
#pragma unroll
    for (int k = 0; k < 7; ++k) acc += xr[k] * nw[k * HID + j];
    h16[idx] = f2bf(acc);
  }
}

// ---------------- histogram ----------------
__global__ void k_hist(const int* __restrict__ dst, int* __restrict__ deg, int nE) {
  int e = blockIdx.x * blockDim.x + threadIdx.x;
  if (e < nE) atomicAdd(&deg[dst[e]], 1);
}

// ---------------- ordered scan cascade (deterministic CSR layout) ----------------
__global__ void k_scanA(const int* __restrict__ deg, int* __restrict__ bsum) {
  __shared__ int ss[256];
  int t = threadIdx.x;
  ss[t] = deg[blockIdx.x * 256 + t];
  __syncthreads();
  for (int off = 128; off; off >>= 1) {
    if (t < off) ss[t] += ss[t + off];
    __syncthreads();
  }
  if (t == 0) bsum[blockIdx.x] = ss[0];
}

__global__ void k_scanB(const int* __restrict__ bsum, int* __restrict__ bsumx, int NB) {
  __shared__ int sd[512];
  int t = threadIdx.x;
  int v = (t < NB) ? bsum[t] : 0;
  sd[t] = v;
  __syncthreads();
  for (int off = 1; off < 512; off <<= 1) {
    int a = (t >= off) ? sd[t - off] : 0;
    __syncthreads();
    sd[t] += a;
    __syncthreads();
  }
  if (t < NB) bsumx[t] = sd[t] - v;
}

// exclusive scan to BOTH cursor (mutated by scatter) and rowptr (kept)
__global__ void k_scanC(const int* __restrict__ deg, const int* __restrict__ bsumx,
                        int* __restrict__ cursor, int* __restrict__ rowptr) {
  __shared__ int ss[256];
  int t = threadIdx.x, i = blockIdx.x * 256 + t;
  int v = deg[i];
  ss[t] = v;
  __syncthreads();
  for (int off = 1; off < 256; off <<= 1) {
    int a = (t >= off) ? ss[t - off] : 0;
    __syncthreads();
    ss[t] += a;
    __syncthreads();
  }
  int ex = ss[t] - v + bsumx[blockIdx.x];
  cursor[i] = ex;
  rowptr[i] = ex;
}

// permute: only src and edge id (8 B random writes; ea gathered later from L3)
__global__ void k_scatter(const int* __restrict__ src, const int* __restrict__ dst,
                          int* __restrict__ cursor,
                          int* __restrict__ src_s, int* __restrict__ esort, int nE) {
  int e = blockIdx.x * blockDim.x + threadIdx.x;
  if (e >= nE) return;
  int d = dst[e];
  int pos = atomicAdd(&cursor[d], 1);
  src_s[pos] = src[e];
  esort[pos] = e;
}

// ---------------- one-time edge encoder GEMM -> e8 (fp8, sorted order) ----------------
// gathers ea rows through esort (ea is L3-resident)
__global__ void __launch_bounds__(256) k_edge_gemm(
    const float* __restrict__ ea, const int* __restrict__ esort,
    const float* __restrict__ ew1, const float* __restrict__ eb1,
    const unsigned short* __restrict__ w2t, const float* __restrict__ eb2,
    unsigned char* __restrict__ e8, int nE) {
  __shared__ __attribute__((aligned(16))) unsigned short ts1[128 * LDP];
  __shared__ float eaL[384];
  __shared__ int esL[128];
  int tid = threadIdx.x;
  int e0 = blockIdx.x * 128;                      // nE % 128 == 0
  if (tid < 128) esL[tid] = esort[e0 + tid];
  __syncthreads();
  for (int i = tid; i < 384; i += 256) {
    int r = i / 3, c = i - r * 3;
    eaL[i] = ea[(size_t)esL[r] * 3 + c];
  }
  __syncthreads();
  {
    int j = tid & 127, r0 = (tid >> 7) * 64;
    float wa = ew1[j], wb = ew1[HID + j], wc = ew1[2 * HID + j], bj = eb1[j];
    for (int r = r0; r < r0 + 64; ++r) {
      float a = bj + eaL[r * 3] * wa + eaL[r * 3 + 1] * wb + eaL[r * 3 + 2] * wc;
      ts1[r * LDP + j] = f2bf(fmaxf(a, 0.f));
    }
  }
  __syncthreads();
  int wave = tid >> 6, lane = tid & 63;
  int l15 = lane & 15, quad = lane >> 4;
  int rbase = (wave >> 1) * 64, nbase = (wave & 1) * 64;
  f32x4 acc[4][4];
#pragma unroll
  for (int i = 0; i < 4; ++i)
#pragma unroll
    for (int j = 0; j < 4; ++j) acc[i][j] = (f32x4){0.f, 0.f, 0.f, 0.f};
  for (int kc = 0; kc < 4; ++kc) {
    int k0 = kc * 32 + quad * 8;
    s16x8 af[4], bf[4];
#pragma unroll
    for (int t = 0; t < 4; ++t)
      af[t] = *(const s16x8*)&ts1[(rbase + t * 16 + l15) * LDP + k0];
#pragma unroll
    for (int t = 0; t < 4; ++t)
      bf[t] = *(const s16x8*)&w2t[(size_t)(nbase + t * 16 + l15) * HID + k0];
#pragma unroll
    for (int i = 0; i < 4; ++i)
#pragma unroll
      for (int j = 0; j < 4; ++j)
        acc[i][j] = __builtin_amdgcn_mfma_f32_16x16x32_bf16(af[i], bf[j], acc[i][j], 0, 0, 0);
  }
  float ebv[4];
#pragma unroll
  for (int t = 0; t < 4; ++t) ebv[t] = eb2[nbase + t * 16 + l15];
#pragma unroll
  for (int tr = 0; tr < 4; ++tr)
#pragma unroll
    for (int reg = 0; reg < 4; ++reg) {
      int row = rbase + tr * 16 + quad * 4 + reg;   // C/D: col=lane&15, row=quad*4+reg
#pragma unroll
      for (int tc = 0; tc < 4; ++tc) {
        int col = nbase + tc * 16 + l15;
        e8[(size_t)(e0 + row) * HID + col] = f2fp8(acc[tr][tc][reg] + ebv[tc]);
      }
    }
}

// ---------------- fused CSR-aggregate + conv MLP, 32-node tile (round-0 verbatim) ----------------
// phase A (16B/lane, fp8 e): node-aligned groups of 4 edges; quad q owns edge
//   gb+q; lane covers 8 cols: e via uint2 (8 B fp8), h via uint4 (16 B bf16).
//   fp32 per-quad partials; node-end: shfl_xor butterfly + quad-0 b128 RMW.
__global__ void __launch_bounds__(256) k_conv_csr(
    const unsigned short* __restrict__ h16in, const unsigned char* __restrict__ e8,
    const int* __restrict__ src_s, const int* __restrict__ rowptr,
    const unsigned short* __restrict__ w1t, const float* __restrict__ b1,
    const unsigned short* __restrict__ w2t, const float* __restrict__ b2,
    unsigned short* __restrict__ h16out, int nN) {
  __shared__ __attribute__((aligned(16))) unsigned short zs[32 * LDP];
  __shared__ int rpS[4][12];
  int tid = threadIdx.x;
  int n0 = blockIdx.x * 32;
  int wave = tid >> 6, lane = tid & 63;
  int l15 = lane & 15, quad = lane >> 4;
  // phase A
  {
    int c16 = l15 * 8;                  // col base (8 cols per lane)
    int c2 = lane * 2;
    int wbase = wave * 8;
    int nodeBase = n0 + wbase;
    int nCnt = nN - nodeBase; if (nCnt > 8) nCnt = 8; if (nCnt < 0) nCnt = 0;
#pragma unroll
    for (int i = 0; i < 8; ++i) {
      int n = nodeBase + i;
      unsigned int hv = 0u;
      if (n < nN) hv = *(const unsigned int*)&h16in[(size_t)n * HID + c2];
      *(unsigned int*)&zs[(wbase + i) * LDP + c2] = hv;
    }
    if (lane < 9) {
      int i = (lane < nCnt) ? lane : nCnt;
      rpS[wave][lane] = (nCnt > 0) ? rowptr[nodeBase + i] : 0;
    }
    if (nCnt > 0) {
      int gb = rpS[wave][0];
      int gEnd = rpS[wave][8];
      int ni = 0;
      while (ni < 8 && rpS[wave][ni + 1] <= gb) ++ni;
      int re = (ni < 8) ? rpS[wave][ni + 1] : gb;
      float acc[8];
#pragma unroll
      for (int j = 0; j < 8; ++j) acc[j] = 0.f;

      int eixA = 0, eixB = 0, eixC = 0, svA = 0, svB = 0, svC = 0;
      int niA = 0, niB = 0, niC = 0;
      bool vA = false, vB = false, vC = false, lA = false, lB = false, lC = false;
      uint2 evA, evB;
      uint4 hvA, hvB;
      bool aA = false, aB = false, aC = false;

#define PS(eix, sv, v, l, nis)                                   \
  { int gq = gb + quad;                                          \
    eix = (gq < re) ? gq : (re - 1);                             \
    v = (gq < re);                                               \
    l = (gb + 4 >= re);                                          \
    nis = ni;                                                    \
    sv = src_s[eix];                                             \
    gb = (gb + 4 < re) ? (gb + 4) : re;                          \
    if (gb >= re) {                                              \
      while (ni < 8 && rpS[wave][ni + 1] <= gb) ++ni;            \
      if (ni < 8) re = rpS[wave][ni + 1];                        \
    } }
#define PEH(ev, hv, eix, sv)                                     \
  { ev = *(const uint2*)&e8[(size_t)eix * HID + c16];            \
    hv = *(const uint4*)&h16in[(size_t)sv * HID + c16]; }
#define FOLDX(ev, hv, v, l, nis)                                 \
  { const unsigned int* ew = (const unsigned int*)&ev;           \
    const unsigned int* hw = (const unsigned int*)&hv;           \
    if (v) {                                                     \
      _Pragma("unroll")                                          \
      for (int j = 0; j < 2; ++j) {                              \
        f32x2 pa = __builtin_amdgcn_cvt_pk_f32_fp8(ew[j], false); \
        f32x2 pb = __builtin_amdgcn_cvt_pk_f32_fp8(ew[j], true);  \
        acc[4*j+0] += fmaxf(asf(hw[2*j] << 16) + pa[0], 0.f);    \
        acc[4*j+1] += fmaxf(asf(hw[2*j] & 0xffff0000u) + pa[1], 0.f); \
        acc[4*j+2] += fmaxf(asf(hw[2*j+1] << 16) + pb[0], 0.f);  \
        acc[4*j+3] += fmaxf(asf(hw[2*j+1] & 0xffff0000u) + pb[1], 0.f); \
      }                                                          \
    }                                                            \
    if (l) {                                                     \
      _Pragma("unroll")                                          \
      for (int j = 0; j < 8; ++j) {                              \
        acc[j] += __shfl_xor(acc[j], 16);                        \
        acc[j] += __shfl_xor(acc[j], 32);                        \
      }                                                          \
      if (quad == 0) {                                           \
        int row = wbase + nis;                                   \
        uint4 z = *(const uint4*)&zs[row * LDP + c16];           \
        unsigned int* zw = (unsigned int*)&z;                    \
        _Pragma("unroll")                                        \
        for (int j = 0; j < 4; ++j) {                            \
          float z0 = asf(zw[j] << 16) + acc[2*j];                \
          float z1 = asf(zw[j] & 0xffff0000u) + acc[2*j+1];      \
          zw[j] = (unsigned int)f2bf(z0) | ((unsigned int)f2bf(z1) << 16); \
        }                                                        \
        *(uint4*)&zs[row * LDP + c16] = z;                       \
      }                                                          \
      _Pragma("unroll")                                          \
      for (int j = 0; j < 8; ++j) acc[j] = 0.f;                  \
    } }

      if (gb < gEnd) { PS(eixA, svA, vA, lA, niA) aA = true; }
      if (gb < gEnd) { PS(eixB, svB, vB, lB, niB) aB = true; }
      if (aA) PEH(evA, hvA, eixA, svA)
      while (aA) {
        aC = (gb < gEnd);
        if (aC) PS(eixC, svC, vC, lC, niC)
        if (aB) PEH(evB, hvB, eixB, svB)
        FOLDX(evA, hvA, vA, lA, niA)
        aA = aB; evA = evB; hvA = hvB; vA = vB; lA = lB; niA = niB; eixA = eixB; svA = svB;
        aB = aC; eixB = eixC; svB = svC; vB = vC; lB = lC; niB = niC;
      }
#undef PS
#undef PEH
#undef FOLDX
    }
  }
  __syncthreads();
  int rbase = (wave >> 1) * 16, nbase = (wave & 1) * 64;
  f32x4 acc[4];
#pragma unroll
  for (int j = 0; j < 4; ++j) acc[j] = (f32x4){0.f, 0.f, 0.f, 0.f};
  for (int kc = 0; kc < 4; ++kc) {
    int k0 = kc * 32 + quad * 8;
    s16x8 af, bf[4];
    af = *(const s16x8*)&zs[(rbase + l15) * LDP + k0];
#pragma unroll
    for (int t = 0; t < 4; ++t)
      bf[t] = *(const s16x8*)&w1t[(size_t)(nbase + t * 16 + l15) * HID + k0];
#pragma unroll
    for (int j = 0; j < 4; ++j)
      acc[j] = __builtin_amdgcn_mfma_f32_16x16x32_bf16(af, bf[j], acc[j], 0, 0, 0);
  }
  __syncthreads();
  {
    float bv[4];
#pragma unroll
    for (int t = 0; t < 4; ++t) bv[t] = b1[nbase + t * 16 + l15];
#pragma unroll
    for (int tc = 0; tc < 4; ++tc)
#pragma unroll
      for (int reg = 0; reg < 4; ++reg) {
        int row = rbase + quad * 4 + reg;
        int col = nbase + tc * 16 + l15;
        zs[row * LDP + col] = f2bf(fmaxf(acc[tc][reg] + bv[tc], 0.f));
      }
  }
  __syncthreads();
#pragma unroll
  for (int j = 0; j < 4; ++j) acc[j] = (f32x4){0.f, 0.f, 0.f, 0.f};
  for (int kc = 0; kc < 4; ++kc) {
    int k0 = kc * 32 + quad * 8;
    s16x8 af, bf[4];
    af = *(const s16x8*)&zs[(rbase + l15) * LDP + k0];
#pragma unroll
    for (int t = 0; t < 4; ++t)
      bf[t] = *(const s16x8*)&w2t[(size_t)(nbase + t * 16 + l15) * HID + k0];
#pragma unroll
    for (int j = 0; j < 4; ++j)
      acc[j] = __builtin_amdgcn_mfma_f32_16x16x32_bf16(af, bf[j], acc[j], 0, 0, 0);
  }
  {
    float bv[4];
#pragma unroll
    for (int t = 0; t < 4; ++t) bv[t] = b2[nbase + t * 16 + l15];
#pragma unroll
    for (int reg = 0; reg < 4; ++reg) {
      int grow = n0 + rbase + quad * 4 + reg;
      if (grow < nN) {
#pragma unroll
        for (int tc = 0; tc < 4; ++tc) {
          int col = nbase + tc * 16 + l15;
          h16out[(size_t)grow * HID + col] = f2bf(fmaxf(acc[tc][reg] + bv[tc], 0.f));
        }
      }
    }
  }
}

// ---------------- segment-reduced pool + graph counts (batch sorted) ----------------
__global__ void __launch_bounds__(256) k_pool2(
    const unsigned short* __restrict__ h16, const int* __restrict__ batch,
    float* __restrict__ g, int* __restrict__ cnts, int nN) {
  __shared__ int bL[128];
  int tid = threadIdx.x;
  int n0 = blockIdx.x * 128;
  if (tid < 128) {
    int n = n0 + tid;
    bL[tid] = (n < nN) ? batch[n] : -1;
  }
  __syncthreads();
  int half = tid >> 7, col = tid & 127;
  int rs = half * 64;
  int cur = -1, rl = 0;
  float s = 0.f;
  for (int r = rs; r < rs + 64; ++r) {
    int b = bL[r];
    float v = (b >= 0) ? bf2f((unsigned int)h16[(size_t)(n0 + r) * HID + col]) : 0.f;
    if (b != cur) {
      if (cur >= 0) {
        atomicAdd(&g[(size_t)cur * HID + col], s);
        if (col == 0) atomicAdd(&cnts[cur], rl);
      }
      cur = b; s = v; rl = 1;
    } else { s += v; ++rl; }
  }
  if (cur >= 0) {
    atomicAdd(&g[(size_t)cur * HID + col], s);
    if (col == 0) atomicAdd(&cnts[cur], rl);
  }
}

// ---------------- heads ----------------
__global__ void __launch_bounds__(128) k_head(
    const float* __restrict__ g, const int* __restrict__ counts,
    const float* __restrict__ clw1, const float* __restrict__ clb1,
    const float* __restrict__ clw2, const float* __restrict__ clb2,
    const float* __restrict__ rw1, const float* __restrict__ rb1,
    const float* __restrict__ rw2, const float* __restrict__ rb2,
    float* __restrict__ out, int nG) {
  __shared__ float gs[HID];
  int b = blockIdx.x;
  int tid = threadIdx.x;
  float cnt = fmaxf((float)counts[b], 1.f);
  gs[tid] = g[b * HID + tid] / cnt;
  __syncthreads();
  int wave = tid >> 6, lane = tid & 63;
  const float* w1 = wave ? rw1 : clw1;
  const float* b1 = wave ? rb1 : clb1;
  const float* w2 = wave ? rw2 : clw2;
  const float* b2 = wave ? rb2 : clb2;
  float acc = b1[lane];
  for (int k = 0; k < HID; ++k) acc += gs[k] * w1[k * 64 + lane];
  acc = fmaxf(acc, 0.f) * w2[lane];
#pragma unroll
  for (int off = 32; off; off >>= 1) acc += __shfl_down(acc, off);
  if (lane == 0) out[wave * nG + b] = acc + b2[0];
}

extern "C" void kernel_launch(void* const* d_in, const int* in_sizes, int n_in,
                              void* d_out, int out_size, void* d_ws, size_t ws_size,
                              hipStream_t stream) {
  const float* x      = (const float*)d_in[0];
  const float* ea     = (const float*)d_in[1];
  const int*   eidx   = (const int*)d_in[2];
  const int*   batch  = (const int*)d_in[3];
  const float* node_w = (const float*)d_in[4];
  const float* node_b = (const float*)d_in[5];
  const float* ew1    = (const float*)d_in[6];
  const float* eb1    = (const float*)d_in[7];
  const float* ew2    = (const float*)d_in[8];
  const float* eb2    = (const float*)d_in[9];
  const float* cw1    = (const float*)d_in[10];
  const float* cb1    = (const float*)d_in[11];
  const float* cw2    = (const float*)d_in[12];
  const float* cb2    = (const float*)d_in[13];
  const float* clw1   = (const float*)d_in[14];
  const float* clb1   = (const float*)d_in[15];
  const float* clw2   = (const float*)d_in[16];
  const float* clb2   = (const float*)d_in[17];
  const float* rw1    = (const float*)d_in[18];
  const float* rb1    = (const float*)d_in[19];
  const float* rw2    = (const float*)d_in[20];
  const float* rb2    = (const float*)d_in[21];
  float* out = (float*)d_out;

  int nN = in_sizes[3];        // 100000
  int nE = in_sizes[2] / 2;    // 640000 (divisible by 128)
  int nG = out_size / 2;       // 2048
  const int* src = eidx;
  const int* dst = eidx + nE;

  int NB = (nN + 255) / 256;
  int bins = NB * 256;

  // ---- workspace (~140 MB) ----
  size_t hN = (size_t)nN * HID;
  size_t gN = (size_t)nG * HID;
  float* g    = (float*)d_ws;                       // gN
  int*   cnts = (int*)(g + gN);                     // nG
  unsigned short* wT   = (unsigned short*)(cnts + nG);  // 7*16384
  unsigned short* h16a = wT + 7 * 16384;            // hN
  unsigned short* h16b = h16a + hN;                 // hN
  int* deg    = (int*)(h16b + hN);                  // bins
  int* cursor = deg + bins;                         // bins
  int* rowptr = cursor + bins;                      // bins
  int* bsum   = rowptr + bins;                      // 512
  int* bsumx  = bsum + 512;                         // 512
  int* src_s  = bsumx + 512;                        // nE
  int* esort  = src_s + nE;                         // nE
  unsigned char* e8 = (unsigned char*)(esort + nE); // nE*128 fp8

  int nzd4 = bins / 4;                              // deg zero, float4 units
  int nzg4 = (int)((gN + nG) / 4);                  // g + cnts
  int bZD = (nzd4 + 255) / 256;
  int bZG = (nzg4 + 255) / 256;
  int bPW = (7 * 16384) / 256;                      // 448 exact
  int bNE = (nN * HID + 255) / 256;

  k_init<<<bZD + bZG + bPW + bNE, 256, 0, stream>>>(
      (float4*)deg, nzd4, (float4*)g, nzg4,
      ew2, cw1, cw2, wT, x, node_w, node_b, h16a, nN, bZD, bZG, bPW);
  k_hist<<<(nE + 255) / 256, 256, 0, stream>>>(dst, deg, nE);
  k_scanA<<<NB, 256, 0, stream>>>(deg, bsum);
  k_scanB<<<1, 512, 0, stream>>>(bsum, bsumx, NB);
  k_scanC<<<NB, 256, 0, stream>>>(deg, bsumx, cursor, rowptr);
  k_scatter<<<(nE + 255) / 256, 256, 0, stream>>>(src, dst, cursor, src_s, esort, nE);
  k_edge_gemm<<<nE / 128, 256, 0, stream>>>(ea, esort, ew1, eb1, wT, eb2, e8, nE);

  // ping-pong: A->B, B->A, A->B  (final in h16b)
  unsigned short* hin  = h16a;
  unsigned short* hout = h16b;
  for (int l = 0; l < 3; ++l) {
    k_conv_csr<<<(nN + 31) / 32, 256, 0, stream>>>(
        hin, e8, src_s, rowptr,
        wT + (size_t)(1 + l) * 16384, cb1 + (size_t)l * HID,
        wT + (size_t)(4 + l) * 16384, cb2 + (size_t)l * HID, hout, nN);
    unsigned short* t = hin; hin = hout; hout = t;
  }

  k_pool2<<<(nN + 127) / 128, 256, 0, stream>>>(hin, batch, g, cnts, nN);
  k_head<<<nG, 128, 0, stream>>>(g, cnts, clw1, clb1, clw2, clb2,
                                 rw1, rb1, rw2, rb2, out, nG);
}